// Round 5
// baseline (387.451 us; speedup 1.0000x reference)
//
#include <hip/hip_runtime.h>
#include <math.h>

typedef __bf16 bf16x8 __attribute__((ext_vector_type(8)));
typedef float floatx4 __attribute__((ext_vector_type(4)));
typedef unsigned short ushort8_t __attribute__((ext_vector_type(8)));

#define BSZ 8
#define SEQ 2048
#define DIM 512
#define BKEY 32
#define BQ 64
#define NEGB -1.0e30f

__device__ __forceinline__ unsigned short f2bf(float f) {
    unsigned int u = __float_as_uint(f);
    u += 0x7fffu + ((u >> 16) & 1u);   // RNE
    return (unsigned short)(u >> 16);
}
__device__ __forceinline__ float bf2f(unsigned short s) {
    return __uint_as_float(((unsigned int)s) << 16);
}

#define ASYNC16(g, l) __builtin_amdgcn_global_load_lds( \
    (const __attribute__((address_space(1))) unsigned int*)(g), \
    (__attribute__((address_space(3))) unsigned int*)(l), 16, 0, 0)

// ---------- fused pre-pass ----------
// blocks [0,4096): K fp32->bf16 rowmajor. blocks [4096,4608): V -> bf16 tiled-transposed
// Vt[(b*64+kb)*512*32 + d*32 + key], each 32-key tile contiguous (32KB).
__global__ __launch_bounds__(256) void prepass(const float* __restrict__ K,
                                               const float* __restrict__ V,
                                               unsigned short* __restrict__ Kb,
                                               unsigned short* __restrict__ Vt) {
    __shared__ unsigned short T[BKEY][DIM + 8];
    const int j = blockIdx.x, tid = threadIdx.x;
    if (j < 4096) {
        size_t i = ((size_t)j * 256 + tid) * 8;
        float4 a = *(const float4*)(K + i);
        float4 b = *(const float4*)(K + i + 4);
        ushort8_t u;
        u[0]=f2bf(a.x); u[1]=f2bf(a.y); u[2]=f2bf(a.z); u[3]=f2bf(a.w);
        u[4]=f2bf(b.x); u[5]=f2bf(b.y); u[6]=f2bf(b.z); u[7]=f2bf(b.w);
        *(ushort8_t*)(Kb + i) = u;
    } else {
        const int bid = j - 4096;
        const int b = bid & 7, kb = bid >> 3;
        const float* src = V + ((size_t)b * SEQ + (size_t)kb * BKEY) * DIM;
        #pragma unroll
        for (int i = 0; i < 16; ++i) {
            const int idx = i * 256 + tid;
            const int key = idx >> 7;
            const int d = (idx & 127) * 4;
            float4 x = *(const float4*)(src + (size_t)key * DIM + d);
            T[key][d]   = f2bf(x.x);
            T[key][d+1] = f2bf(x.y);
            T[key][d+2] = f2bf(x.z);
            T[key][d+3] = f2bf(x.w);
        }
        __syncthreads();
        unsigned short* dst = Vt + (size_t)(b * (SEQ / BKEY) + kb) * DIM * BKEY;
        #pragma unroll
        for (int i = 0; i < 8; ++i) {
            const int cidx = i * 256 + tid;      // 16B chunk id
            const int d = cidx >> 2, kc = cidx & 3;
            ushort8_t v;
            #pragma unroll
            for (int k2 = 0; k2 < 8; ++k2) v[k2] = T[kc * 8 + k2][d];
            *(ushort8_t*)(dst + cidx * 8) = v;
        }
    }
}

// Work decode per batch (80 items, big chunks first), q-tile = 64 rows:
//  j<32: t=31-(j>>2), c=j&3 | j<56: u=j-32,q3=u/3: t=23-q3,c=u-3q3
//  j<72: u=j-56: t=15-(u>>1), c=u&1 | else: t=7-(j-72), c=0
// chunk c covers kt in [16c, min(16c+16, 2t+2)); decode guarantees t>=8c so the
// first tile of every chunk has >=1 unmasked key per row. split iff t>=8.

template <int SPLIT>
__global__ __launch_bounds__(256, 2)
void attn_fwd(const float* __restrict__ Q,
              const unsigned short* __restrict__ Kb,
              const unsigned short* __restrict__ Vt,
              unsigned short* __restrict__ PartO,
              float* __restrict__ Pml,
              float* __restrict__ O)
{
    __shared__ unsigned short Ksh[BKEY * DIM];   // chunk i <-> (row=i>>6, cc=i&63), holds ch=cc^(row&7)
    __shared__ unsigned short Vsh[DIM * BKEY];   // chunk i <-> (d=i>>2, cc=i&3), holds kc=cc^(d&3)
    __shared__ unsigned short Psh[4 * 16 * BKEY];

    const int tid  = threadIdx.x;
    const int lane = tid & 63;
    const int wv   = tid >> 6;        // wave 0..3
    const int ml   = lane & 15;
    const int quad = lane >> 4;

    const int bid = blockIdx.x;
    const int b   = bid & 7;
    const int j   = bid >> 3;
    int t, c;
    if (SPLIT) {
        if (j < 32)      { t = 31 - (j >> 2); c = j & 3; }
        else if (j < 56) { int u = j - 32; int q3 = u / 3; t = 23 - q3; c = u - q3 * 3; }
        else if (j < 72) { int u = j - 56; t = 15 - (u >> 1); c = u & 1; }
        else             { t = 7 - (j - 72); c = 0; }
    } else { t = 31 - j; c = 0; }
    const int kt0 = c * 16;
    const int kt1 = SPLIT ? min(kt0 + 16, 2 * t + 2) : (2 * t + 2);
    const bool is_split = SPLIT && (t >= 8);
    const int qw = t * BQ + wv * 16;             // wave's first q-row

    const float* Qb = Q + (size_t)b * SEQ * DIM;
    const unsigned short* Kbb = Kb + (size_t)b * SEQ * DIM;
    const unsigned short* Vtb = Vt + (size_t)b * SEQ * DIM;
    float* Ob = O + (size_t)b * SEQ * DIM;

    // ---- Q fragments, A-layout: A[m=ml][k=quad*8+jj] ----
    bf16x8 qf[16];
    {
        const float* qp = Qb + (size_t)(qw + ml) * DIM + quad * 8;
        #pragma unroll
        for (int kc = 0; kc < 16; ++kc) {
            float4 x = *(const float4*)(qp + kc * 32);
            float4 y = *(const float4*)(qp + kc * 32 + 4);
            union { bf16x8 v; unsigned short s[8]; } u;
            u.s[0]=f2bf(x.x); u.s[1]=f2bf(x.y); u.s[2]=f2bf(x.z); u.s[3]=f2bf(x.w);
            u.s[4]=f2bf(y.x); u.s[5]=f2bf(y.y); u.s[6]=f2bf(y.z); u.s[7]=f2bf(y.w);
            qf[kc] = u.v;
        }
    }

    floatx4 acc[32];
    #pragma unroll
    for (int i = 0; i < 32; ++i) acc[i] = (floatx4){0.f, 0.f, 0.f, 0.f};
    // Finite sentinels: every exp2 argument stays finite -> no NaN path exists.
    float mrun[4] = {NEGB, NEGB, NEGB, NEGB};
    float lrun[4] = {0.f, 0.f, 0.f, 0.f};

    const float CS = 1.4426950408889634f * 0.04419417382415922f; // log2(e)/sqrt(512)

    for (int kt = kt0; kt < kt1; ++kt) {
        const int k0 = kt * BKEY;

        __syncthreads();   // all waves done reading prev tile

        // ---- async stage K (8 instr/thread) + V (8 instr/thread) ----
        const unsigned short* Kt = Kbb + (size_t)k0 * DIM;
        #pragma unroll
        for (int i = 0; i < 8; ++i) {
            const int ci  = i * 256 + tid;
            const int row = ci >> 6;
            const int ch  = (ci & 63) ^ (row & 7);
            ASYNC16(Kt + (size_t)row * DIM + ch * 8, &Ksh[ci * 8]);
        }
        const unsigned short* Vtile = Vtb + (size_t)kt * (DIM * BKEY);
        #pragma unroll
        for (int i = 0; i < 8; ++i) {
            const int ci = i * 256 + tid;
            const int d  = ci >> 2;
            const int kc = (ci & 3) ^ (d & 3);
            ASYNC16(Vtile + d * BKEY + kc * 8, &Vsh[ci * 8]);
        }
        __syncthreads();   // vmcnt(0) drain: tile visible to all waves

        // ---- S = Q K^T ----
        floatx4 s0 = (floatx4){0,0,0,0}, s1 = (floatx4){0,0,0,0};
        const int sw = ml & 7;
        #pragma unroll
        for (int kc = 0; kc < 16; ++kc) {
            const int ch = kc * 4 + quad;
            bf16x8 kf0 = *(bf16x8*)&Ksh[ml * DIM + ((ch ^ sw) << 3)];
            bf16x8 kf1 = *(bf16x8*)&Ksh[(16 + ml) * DIM + ((ch ^ sw) << 3)];
            s0 = __builtin_amdgcn_mfma_f32_16x16x32_bf16(qf[kc], kf0, s0, 0, 0, 0);
            s1 = __builtin_amdgcn_mfma_f32_16x16x32_bf16(qf[kc], kf1, s1, 0, 0, 0);
        }

        // ---- online softmax (C-layout: row=quad*4+r, col=nt*16+ml) ----
        float z[2][4], pr[2][4], al[4], rs[4];
        if (kt >= 2 * t) {   // block-uniform: diagonal tiles; predicate exact per lane
            #pragma unroll
            for (int r = 0; r < 4; ++r) {
                const int qg = qw + quad * 4 + r;
                z[0][r] = (k0 + ml > qg)      ? NEGB : s0[r] * CS;
                z[1][r] = (k0 + 16 + ml > qg) ? NEGB : s1[r] * CS;
            }
        } else {
            #pragma unroll
            for (int r = 0; r < 4; ++r) { z[0][r] = s0[r] * CS; z[1][r] = s1[r] * CS; }
        }
        #pragma unroll
        for (int r = 0; r < 4; ++r) {
            float v = fmaxf(z[0][r], z[1][r]);
            v = fmaxf(v, __shfl_xor(v, 1, 64));
            v = fmaxf(v, __shfl_xor(v, 2, 64));
            v = fmaxf(v, __shfl_xor(v, 4, 64));
            v = fmaxf(v, __shfl_xor(v, 8, 64));
            const float nm = fmaxf(mrun[r], v);
            al[r]   = __builtin_amdgcn_exp2f(mrun[r] - nm);   // finite - finite
            mrun[r] = nm;
        }
        #pragma unroll
        for (int r = 0; r < 4; ++r) {
            pr[0][r] = __builtin_amdgcn_exp2f(z[0][r] - mrun[r]);
            pr[1][r] = __builtin_amdgcn_exp2f(z[1][r] - mrun[r]);
            float s = pr[0][r] + pr[1][r];
            s += __shfl_xor(s, 1, 64);
            s += __shfl_xor(s, 2, 64);
            s += __shfl_xor(s, 4, 64);
            s += __shfl_xor(s, 8, 64);
            rs[r] = s;
        }
        #pragma unroll
        for (int r = 0; r < 4; ++r) lrun[r] = lrun[r] * al[r] + rs[r];

        if (al[0] < 1.f || al[1] < 1.f || al[2] < 1.f || al[3] < 1.f) {
            const floatx4 alv = (floatx4){al[0], al[1], al[2], al[3]};
            #pragma unroll
            for (int nt = 0; nt < 32; ++nt) acc[nt] = acc[nt] * alv;
        }

        // ---- P: C-layout -> A-layout via LDS round trip (per-wave region) ----
        unsigned short* Pw = &Psh[wv * (16 * BKEY)];
        #pragma unroll
        for (int nt = 0; nt < 2; ++nt) {
            #pragma unroll
            for (int r = 0; r < 4; ++r) {
                const int row = quad * 4 + r, col = nt * 16 + ml;
                Pw[row * BKEY + ((((col >> 3) ^ (row & 3)) << 3) | (col & 7))] = f2bf(pr[nt][r]);
            }
        }
        __syncthreads();   // hard fence for the P transpose
        bf16x8 pf = *(bf16x8*)&Pw[ml * BKEY + ((quad ^ (ml & 3)) << 3)];

        // ---- O += P V ----
        #pragma unroll
        for (int nt = 0; nt < 32; ++nt) {
            const int drow = nt * 16 + ml;
            bf16x8 vf = *(bf16x8*)&Vsh[drow * BKEY + ((quad ^ (drow & 3)) << 3)];
            acc[nt] = __builtin_amdgcn_mfma_f32_16x16x32_bf16(pf, vf, acc[nt], 0, 0, 0);
        }
    }

    if (!is_split) {
        float inv[4];
        #pragma unroll
        for (int r = 0; r < 4; ++r) inv[r] = 1.f / lrun[r];
        #pragma unroll
        for (int nt = 0; nt < 32; ++nt) {
            #pragma unroll
            for (int r = 0; r < 4; ++r) {
                const int row = qw + quad * 4 + r;
                Ob[(size_t)row * DIM + nt * 16 + ml] = acc[nt][r] * inv[r];
            }
        }
    } else {
        const size_t slot = (size_t)(b * 72 + j);
        unsigned short* po = PartO + slot * (BQ * DIM);
        #pragma unroll
        for (int nt = 0; nt < 32; ++nt) {
            #pragma unroll
            for (int r = 0; r < 4; ++r) {
                const int prow = wv * 16 + quad * 4 + r;
                po[(size_t)prow * DIM + nt * 16 + ml] = f2bf(acc[nt][r]);
            }
        }
        if (ml == 0) {
            #pragma unroll
            for (int r = 0; r < 4; ++r) {
                const int prow = wv * 16 + quad * 4 + r;
                Pml[slot * 128 + prow * 2]     = mrun[r];
                Pml[slot * 128 + prow * 2 + 1] = lrun[r];
            }
        }
    }
}

// ---------- merge: combine nc=2..4 chunk partials per (b, t>=8, half) ----------
__global__ __launch_bounds__(256)
void attn_merge(const unsigned short* __restrict__ PartO,
                const float* __restrict__ Pml,
                float* __restrict__ O)
{
    const int bid  = blockIdx.x;          // 8 * 24 * 2
    const int b    = bid & 7;
    const int rest = bid >> 3;
    const int t    = 8 + (rest >> 1);
    const int half = rest & 1;
    const int nc   = t / 8 + 1;
    int j0;
    if (t >= 24)      j0 = (31 - t) * 4;
    else if (t >= 16) j0 = 32 + (23 - t) * 3;
    else              j0 = 56 + (15 - t) * 2;

    const int r  = half * 32 + (threadIdx.x >> 3);   // partial row 0..63
    const int d0 = (threadIdx.x & 7) * 64;

    float m[4], l[4];
    float M = NEGB;
    #pragma unroll
    for (int cc = 0; cc < 4; ++cc) {
        if (cc < nc) {
            const size_t slot = (size_t)(b * 72 + j0 + cc);
            m[cc] = Pml[slot * 128 + r * 2];
            l[cc] = Pml[slot * 128 + r * 2 + 1];
            M = fmaxf(M, m[cc]);
        }
    }
    float L = 0.f;
    #pragma unroll
    for (int cc = 0; cc < 4; ++cc)
        if (cc < nc) L += l[cc] * __builtin_amdgcn_exp2f(m[cc] - M);

    float o[64];
    #pragma unroll
    for (int i = 0; i < 64; ++i) o[i] = 0.f;
    #pragma unroll
    for (int cc = 0; cc < 4; ++cc) {
        if (cc < nc) {
            const size_t slot = (size_t)(b * 72 + j0 + cc);
            const float w = __builtin_amdgcn_exp2f(m[cc] - M);
            const unsigned short* po = PartO + slot * (BQ * DIM) + (size_t)r * DIM + d0;
            #pragma unroll
            for (int i = 0; i < 8; ++i) {
                ushort8_t v = *(const ushort8_t*)(po + i * 8);
                #pragma unroll
                for (int k2 = 0; k2 < 8; ++k2) o[i * 8 + k2] += w * bf2f(v[k2]);
            }
        }
    }
    const float invL = 1.f / L;
    float* out = O + ((size_t)b * SEQ + (size_t)t * BQ + r) * DIM + d0;
    #pragma unroll
    for (int i = 0; i < 16; ++i) {
        float4 v4 = { o[i*4] * invL, o[i*4+1] * invL, o[i*4+2] * invL, o[i*4+3] * invL };
        *(float4*)(out + i * 4) = v4;
    }
}

extern "C" void kernel_launch(void* const* d_in, const int* in_sizes, int n_in,
                              void* d_out, int out_size, void* d_ws, size_t ws_size,
                              hipStream_t stream) {
    const float* Q = (const float*)d_in[0];
    const float* K = (const float*)d_in[1];
    const float* V = (const float*)d_in[2];
    float* Out = (float*)d_out;

    const size_t elems = (size_t)BSZ * SEQ * DIM;
    unsigned short* Kb = (unsigned short*)d_ws;
    unsigned short* Vt = Kb + elems;
    unsigned short* PartO = Vt + elems;
    float* Pml = (float*)(PartO + (size_t)BSZ * 72 * BQ * DIM);

    const size_t need_split = 2 * elems * 2
                            + (size_t)BSZ * 72 * BQ * DIM * 2
                            + (size_t)BSZ * 72 * 128 * 4;

    prepass<<<dim3(4096 + 512), dim3(256), 0, stream>>>(K, V, Kb, Vt);

    if (ws_size >= need_split) {
        attn_fwd<1><<<dim3(BSZ * 80), dim3(256), 0, stream>>>(Q, Kb, Vt, PartO, Pml, Out);
        attn_merge<<<dim3(BSZ * 48), dim3(256), 0, stream>>>(PartO, Pml, Out);
    } else {
        attn_fwd<0><<<dim3(BSZ * 32), dim3(256), 0, stream>>>(Q, Kb, Vt, PartO, Pml, Out);
    }
}